// Round 1
// baseline (251.549 us; speedup 1.0000x reference)
//
#include <hip/hip_runtime.h>

// Problem constants (fixed by the reference)
#define N0        200000
#define N1        25000
#define N2        5000
#define FANOUT    16
#define IN_FEATS  500
#define N_HIDDEN  128
#define N_CLASSES 47

constexpr int R1 = 8;   // rows per block, kernel 1
constexpr int R2 = 8;   // rows per block, kernel 2

// Kernel 1: fused gather-mean over features + Linear(W1,b1) + concat(h, relu(h))
// Output: h1cat [N1, 2*N_HIDDEN] into workspace.
__global__ __launch_bounds__(256) void k1_gather_gemm(
    const float* __restrict__ features,   // [N0, IN_FEATS]
    const int*   __restrict__ src0,       // [N1, FANOUT]
    const float* __restrict__ W1,         // [IN_FEATS, N_HIDDEN]
    const float* __restrict__ b1,         // [N_HIDDEN]
    float*       __restrict__ h1cat)      // [N1, 2*N_HIDDEN]
{
    __shared__ float sm[R1][IN_FEATS];        // mean-aggregated rows (16 KB)
    __shared__ int   snb[R1 * FANOUT];

    const int tid  = threadIdx.x;
    const int row0 = blockIdx.x * R1;

    if (tid < R1 * FANOUT) snb[tid] = src0[row0 * FANOUT + tid];
    __syncthreads();

    // Phase 1: gather + mean. Coalesced across threads (consecutive f).
    for (int r = 0; r < R1; ++r) {
        for (int f = tid; f < IN_FEATS; f += 256) {
            float acc = 0.f;
            #pragma unroll
            for (int j = 0; j < FANOUT; ++j) {
                acc += features[(size_t)snb[r * FANOUT + j] * IN_FEATS + f];
            }
            sm[r][f] = acc * (1.0f / FANOUT);
        }
    }
    __syncthreads();

    // Phase 2: GEMM  [R1 x IN_FEATS] @ [IN_FEATS x N_HIDDEN].
    // Thread t computes column c = t&127 for 4 rows (rg selects row group).
    // sm reads are wave-uniform broadcasts (rg is uniform per wave).
    const int c  = tid & (N_HIDDEN - 1);
    const int rg = tid >> 7;   // 0 or 1
    float acc[4] = {0.f, 0.f, 0.f, 0.f};

    #pragma unroll 4
    for (int k = 0; k < IN_FEATS; ++k) {
        const float w = W1[k * N_HIDDEN + c];   // coalesced 512B/row, L2-resident
        #pragma unroll
        for (int i = 0; i < 4; ++i)
            acc[i] += sm[rg * 4 + i][k] * w;
    }

    const float bias = b1[c];
    #pragma unroll
    for (int i = 0; i < 4; ++i) {
        const int row = row0 + rg * 4 + i;
        const float h = acc[i] + bias;
        h1cat[(size_t)row * (2 * N_HIDDEN) + c]            = h;
        h1cat[(size_t)row * (2 * N_HIDDEN) + N_HIDDEN + c] = h > 0.f ? h : 0.f;
    }
}

// Kernel 2: gather-mean over h1cat + Linear(W2,b2) -> out [N2, N_CLASSES]
__global__ __launch_bounds__(256) void k2_gather_gemm(
    const float* __restrict__ h1cat,      // [N1, 2*N_HIDDEN]
    const int*   __restrict__ src1,       // [N2, FANOUT]
    const float* __restrict__ W2,         // [2*N_HIDDEN, N_CLASSES]
    const float* __restrict__ b2,         // [N_CLASSES]
    float*       __restrict__ out)        // [N2, N_CLASSES]
{
    __shared__ float sm[R2][2 * N_HIDDEN];    // 8 KB
    __shared__ int   snb[R2 * FANOUT];

    const int tid  = threadIdx.x;
    const int row0 = blockIdx.x * R2;

    if (tid < R2 * FANOUT) snb[tid] = src1[row0 * FANOUT + tid];
    __syncthreads();

    // Phase 1: gather + mean. One feature per thread (2*N_HIDDEN == 256).
    for (int r = 0; r < R2; ++r) {
        float acc = 0.f;
        #pragma unroll
        for (int j = 0; j < FANOUT; ++j)
            acc += h1cat[(size_t)snb[r * FANOUT + j] * (2 * N_HIDDEN) + tid];
        sm[r][tid] = acc * (1.0f / FANOUT);
    }
    __syncthreads();

    // Phase 2: small GEMM [R2 x 256] @ [256 x 47] + bias.
    for (int o = tid; o < R2 * N_CLASSES; o += 256) {
        const int r = o / N_CLASSES;
        const int c = o % N_CLASSES;
        float acc = b2[c];
        #pragma unroll 4
        for (int k = 0; k < 2 * N_HIDDEN; ++k)
            acc += sm[r][k] * W2[k * N_CLASSES + c];
        out[(size_t)(row0 + r) * N_CLASSES + c] = acc;
    }
}

extern "C" void kernel_launch(void* const* d_in, const int* in_sizes, int n_in,
                              void* d_out, int out_size, void* d_ws, size_t ws_size,
                              hipStream_t stream)
{
    const float* features = (const float*)d_in[0];
    const int*   src0     = (const int*)  d_in[1];
    const int*   src1     = (const int*)  d_in[2];
    const float* W1       = (const float*)d_in[3];
    const float* b1       = (const float*)d_in[4];
    const float* W2       = (const float*)d_in[5];
    const float* b2       = (const float*)d_in[6];
    float*       out      = (float*)d_out;
    float*       h1cat    = (float*)d_ws;   // [N1, 2*N_HIDDEN] = 25.6 MB

    hipLaunchKernelGGL(k1_gather_gemm, dim3(N1 / R1), dim3(256), 0, stream,
                       features, src0, W1, b1, h1cat);
    hipLaunchKernelGGL(k2_gather_gemm, dim3(N2 / R2), dim3(256), 0, stream,
                       h1cat, src1, W2, b2, out);
}